// Round 6
// baseline (278.332 us; speedup 1.0000x reference)
//
#include <hip/hip_runtime.h>
#include <hip/hip_bf16.h>

typedef __bf16 bf16x8 __attribute__((ext_vector_type(8)));
typedef __bf16 bf16x4 __attribute__((ext_vector_type(4)));
typedef float  f32x4  __attribute__((ext_vector_type(4)));
typedef int    i32x4  __attribute__((ext_vector_type(4)));

#define MFMA16(a,b,c) __builtin_amdgcn_mfma_f32_16x16x32_bf16((a),(b),(c),0,0,0)

static constexpr int Tt = 256;   // seq len
static constexpr int Cc = 384;   // embed
static constexpr int Hh = 6;     // heads
static constexpr int Dd = 64;    // head dim
static constexpr int HD = 384;   // H*D
static constexpr int NQ = 1152;  // 3*H*D

// async global->LDS, 16B per lane; lds base must be wave-uniform
__device__ __forceinline__ void gload16(const void* g, void* l) {
  __builtin_amdgcn_global_load_lds(
      (const __attribute__((address_space(1))) void*)g,
      (__attribute__((address_space(3))) void*)l, 16, 0, 0);
}

// ---------------- xcast: x fp32 -> bf16 ----------------
__global__ __launch_bounds__(256) void xcast(
    const float* __restrict__ x, __bf16* __restrict__ xb)
{
  size_t i = (size_t)blockIdx.x * 256 + threadIdx.x;
  const float4* p = (const float4*)(x + i * 8);
  float4 a = p[0], b = p[1];
  bf16x8 o;
  o[0] = (__bf16)a.x; o[1] = (__bf16)a.y; o[2] = (__bf16)a.z; o[3] = (__bf16)a.w;
  o[4] = (__bf16)b.x; o[5] = (__bf16)b.y; o[6] = (__bf16)b.z; o[7] = (__bf16)b.w;
  *(bf16x8*)(xb + i * 8) = o;
}

// ---------------- prep: convert/transpose weights to bf16 ----------------
__global__ __launch_bounds__(256) void prep_w(
    const float* __restrict__ wq, const float* __restrict__ wk,
    const float* __restrict__ wv, const float* __restrict__ wp,
    __bf16* __restrict__ wqkvb, __bf16* __restrict__ wpb)
{
  int idx = blockIdx.x * 256 + threadIdx.x;
  const int n1 = NQ * Cc;  // 442368
  if (idx < n1) {
    int n = idx / Cc, c = idx % Cc;
    int which = n / HD, r = n % HD, h = r >> 6, d = r & 63;
    const float* w = which == 0 ? wq : (which == 1 ? wk : wv);
    wqkvb[idx] = (__bf16)w[(h * Cc + c) * Dd + d];
  } else {
    int j = idx - n1;
    if (j < Cc * HD) {
      int co = j / HD, ci = j % HD;
      wpb[j] = (__bf16)wp[ci * Cc + co];
    }
  }
}

// ---------------- GEMM 1: QKV projection ----------------
__global__ __launch_bounds__(256) void gemm_qkv(
    const __bf16* __restrict__ xb, const __bf16* __restrict__ wn,
    __bf16* __restrict__ qkv, int Mc)
{
  __shared__ __align__(16) char smem[36864];
  char* Al = smem;            // [128 rows][128B], slot s holds global slot s^(row&7)
  char* Bl = smem + 16384;

  const int tid = threadIdx.x;
  const int m0 = blockIdx.x * 128;
  const int n0 = blockIdx.y * 128;
  const int wid = tid >> 6, ln = tid & 63;
  const int wm = wid >> 1, wn_ = wid & 1;
  const int lr = ln & 15, lg = ln >> 4;
  const int srow = ln >> 3, sslot = ln & 7;

  f32x4 acc[4][4];
#pragma unroll
  for (int i = 0; i < 4; ++i)
#pragma unroll
    for (int j = 0; j < 4; ++j) acc[i][j] = f32x4{0.f, 0.f, 0.f, 0.f};

  for (int kt = 0; kt < Cc; kt += 64) {
#pragma unroll
    for (int i = 0; i < 4; ++i) {
      int off = (wid * 4 + i) << 10;
      int row = (off >> 7) + srow;
      gload16(xb + (size_t)(m0 + row) * Cc + kt + ((sslot ^ (row & 7)) << 3), Al + off);
    }
#pragma unroll
    for (int i = 0; i < 4; ++i) {
      int off = (wid * 4 + i) << 10;
      int row = (off >> 7) + srow;
      gload16(wn + (size_t)(n0 + row) * Cc + kt + ((sslot ^ (row & 7)) << 3), Bl + off);
    }
    __syncthreads();
#pragma unroll
    for (int ks = 0; ks < 2; ++ks) {
      bf16x8 af[4], bfr[4];
#pragma unroll
      for (int mi = 0; mi < 4; ++mi) {
        int r = wm * 64 + mi * 16 + lr;
        af[mi] = *(const bf16x8*)(Al + r * 128 + (((ks * 4 + lg) ^ (r & 7)) << 4));
      }
#pragma unroll
      for (int ni = 0; ni < 4; ++ni) {
        int r = wn_ * 64 + ni * 16 + lr;
        bfr[ni] = *(const bf16x8*)(Bl + r * 128 + (((ks * 4 + lg) ^ (r & 7)) << 4));
      }
      __builtin_amdgcn_s_setprio(1);
#pragma unroll
      for (int mi = 0; mi < 4; ++mi)
#pragma unroll
        for (int ni = 0; ni < 4; ++ni)
          acc[mi][ni] = MFMA16(af[mi], bfr[ni], acc[mi][ni]);
      __builtin_amdgcn_s_setprio(0);
    }
    __syncthreads();
  }

  // epilogue: stage C tile in LDS, then coalesced 16B scatter-stores
  __bf16* Cl = (__bf16*)smem;  // [128][136] (272B stride), 34816 B
#pragma unroll
  for (int mi = 0; mi < 4; ++mi)
#pragma unroll
    for (int ni = 0; ni < 4; ++ni)
#pragma unroll
      for (int j = 0; j < 4; ++j) {
        int row = wm * 64 + mi * 16 + lg * 4 + j;
        int col = wn_ * 64 + ni * 16 + lr;
        *((__bf16*)((char*)Cl + row * 272 + col * 2)) = (__bf16)acc[mi][ni][j];
      }
  __syncthreads();
#pragma unroll
  for (int p = 0; p < 8; ++p) {
    int row = p * 16 + (tid >> 4);
    int ch = tid & 15;
    bf16x8 v = *(const bf16x8*)((char*)Cl + row * 272 + ch * 16);
    int m = m0 + row, n = n0 + ch * 8;
    int which = n / HD, r = n % HD, h = r >> 6, d = r & 63;
    int bl = m >> 8, t = m & 255;
    *(bf16x8*)(qkv + (size_t)which * ((size_t)Mc * HD) +
               ((size_t)(bl * Hh + h) * Tt + t) * Dd + d) = v;
  }
}

// ---------------- Attention v2c: swapped QK^T, in-register P (union pack) ----------------
__global__ __launch_bounds__(512, 4) void attn_k(
    const __bf16* __restrict__ q, const __bf16* __restrict__ k,
    const __bf16* __restrict__ v, __bf16* __restrict__ att)
{
  __shared__ __align__(128) char smem[65536];
  char* Kl = smem;           // [256 keys][128B], 16B-slot s holds global slot s^(key&7)
  char* Vl = smem + 32768;   // [64][256] bf16 (transposed), byte ^ ((d&7)<<4)  [R2/R3-verified]

  const int bh = blockIdx.x;
  const int tid = threadIdx.x, wid = tid >> 6, lane = tid & 63;
  const int lr = lane & 15, lg = lane >> 4;
  const size_t base = (size_t)bh * (Tt * Dd);

  // stage K: linear dest, pre-swizzled source
#pragma unroll
  for (int i = 0; i < 4; ++i) {
    int off = (wid * 4 + i) << 10;
    int row = (off >> 7) + (lane >> 3);
    int slot = lane & 7;
    gload16(k + base + row * 64 + ((slot ^ (row & 7)) << 3), Kl + off);
  }
  // stage V transposed (scalar writes, swizzled) — verified R2/R3 pattern
#pragma unroll
  for (int i = 0; i < 4; ++i) {
    int chunk = tid + 512 * i;           // 2048 chunks of 8 bf16
    int key = chunk >> 3, d8 = chunk & 7;
    bf16x8 vv = *(const bf16x8*)(v + base + key * 64 + d8 * 8);
#pragma unroll
    for (int e = 0; e < 8; ++e) {
      int d = d8 * 8 + e;
      *(__bf16*)(Vl + ((d * 512 + key * 2) ^ ((d & 7) << 4))) = vv[e];
    }
  }
  __syncthreads();

  const int bl = bh / Hh, h = bh % Hh;

  for (int qi = 0; qi < 2; ++qi) {
    const int qt = (qi == 0) ? wid : 15 - wid;   // q-tile 0..15, balanced pairing
    const int qbase = qt * 16;

    // Q as B-fragment: col = q_local = lr, k = lg*8+e
    bf16x8 qf0 = *(const bf16x8*)(q + base + (qbase + lr) * 64 + lg * 8);
    bf16x8 qf1 = *(const bf16x8*)(q + base + (qbase + lr) * 64 + 32 + lg * 8);

    // swapped QK^T: s[n][j] = S[key = n*16 + 4*lg + j][q = qbase + lr]
    f32x4 s[16];
#pragma unroll
    for (int n = 0; n < 16; ++n) s[n] = f32x4{0.f, 0.f, 0.f, 0.f};
    __builtin_amdgcn_s_setprio(1);
#pragma unroll
    for (int n = 0; n < 16; ++n) {
      if (n <= qt) {
        int rowb = (n * 16 + lr) * 128;
        int swz = (lr & 7) << 4;
        bf16x8 k0 = *(const bf16x8*)(Kl + ((rowb + lg * 16) ^ swz));
        bf16x8 k1 = *(const bf16x8*)(Kl + ((rowb + 64 + lg * 16) ^ swz));
        s[n] = MFMA16(k0, qf0, s[n]);
        s[n] = MFMA16(k1, qf1, s[n]);
      }
    }
    __builtin_amdgcn_s_setprio(0);

    // scale + causal mask (only diagonal tile partially masked)
    float mx = -1e30f;
#pragma unroll
    for (int n = 0; n < 16; ++n) {
      if (n <= qt) {
#pragma unroll
        for (int j = 0; j < 4; ++j) {
          float sv = s[n][j] * 0.125f;
          if (n == qt && 4 * lg + j > lr) sv = -1e30f;
          s[n][j] = sv;
          mx = fmaxf(mx, sv);
        }
      }
    }
    mx = fmaxf(mx, __shfl_xor(mx, 16));
    mx = fmaxf(mx, __shfl_xor(mx, 32));

    // exp + row-sum + pack P to bf16 words (unnormalized; normalize at epilogue)
    float sum = 0.f;
    int w[16][2];
#pragma unroll
    for (int n = 0; n < 16; ++n) {
      if (n <= qt) {
        float e0 = __expf(s[n][0] - mx);
        float e1 = __expf(s[n][1] - mx);
        float e2 = __expf(s[n][2] - mx);
        float e3 = __expf(s[n][3] - mx);
        sum += (e0 + e1) + (e2 + e3);
        union { __bf16 hh[2]; int ii; } u0, u1;
        u0.hh[0] = (__bf16)e0; u0.hh[1] = (__bf16)e1;
        u1.hh[0] = (__bf16)e2; u1.hh[1] = (__bf16)e3;
        w[n][0] = u0.ii;
        w[n][1] = u1.ii;
      } else if (n == (qt | 1)) {
        w[n][0] = 0; w[n][1] = 0;   // zero pad tile read by PV when qt is even
      }
    }
    sum += __shfl_xor(sum, 16);
    sum += __shfl_xor(sum, 32);
    float inv = 1.0f / sum;

    // PV: A = P (shuffle dance, in-register), B = V via swizzled b128 reads
    f32x4 o[4];
#pragma unroll
    for (int dn = 0; dn < 4; ++dn) o[dn] = f32x4{0.f, 0.f, 0.f, 0.f};
    const int kkmax = qt >> 1;
#pragma unroll
    for (int kk = 0; kk < 8; ++kk) {
      if (kk <= kkmax) {
        // A-fragment: lane (lr,lg) needs P[q=lr][key = kk*32 + lg*8 + 2r + {0,1}]
        int s0 = lr + ((lg & 1) << 5);
        int s1 = s0 + 16;
        int hi = lg >> 1;
        int a0 = __shfl(w[2 * kk][0], s0), b0 = __shfl(w[2 * kk + 1][0], s0);
        int a1 = __shfl(w[2 * kk][1], s0), b1 = __shfl(w[2 * kk + 1][1], s0);
        int a2 = __shfl(w[2 * kk][0], s1), b2 = __shfl(w[2 * kk + 1][0], s1);
        int a3 = __shfl(w[2 * kk][1], s1), b3 = __shfl(w[2 * kk + 1][1], s1);
        i32x4 pwv;
        pwv[0] = hi ? b0 : a0;
        pwv[1] = hi ? b1 : a1;
        pwv[2] = hi ? b2 : a2;
        pwv[3] = hi ? b3 : a3;
        bf16x8 pa = __builtin_bit_cast(bf16x8, pwv);

        __builtin_amdgcn_s_setprio(1);
#pragma unroll
        for (int dn = 0; dn < 4; ++dn) {
          int d = dn * 16 + lr;
          bf16x8 vb = *(const bf16x8*)(Vl + ((d * 512 + kk * 64 + lg * 16) ^ ((d & 7) << 4)));
          o[dn] = MFMA16(pa, vb, o[dn]);
        }
        __builtin_amdgcn_s_setprio(0);
      }
    }

    // epilogue: O[q = qbase + 4*lg + j][d = dn*16 + lr], normalized by 1/sum(q)
#pragma unroll
    for (int j = 0; j < 4; ++j) {
      float invj = __shfl(inv, lg * 4 + j, 16);
      int qrow = qbase + lg * 4 + j;
#pragma unroll
      for (int dn = 0; dn < 4; ++dn)
        att[((size_t)(bl * Tt + qrow)) * HD + h * Dd + dn * 16 + lr] =
            (__bf16)(o[dn][j] * invj);
    }
  }
}

// ---------------- GEMM 2: output projection + bias ----------------
__global__ __launch_bounds__(256) void gemm_out(
    const __bf16* __restrict__ att, const __bf16* __restrict__ wpb,
    const float* __restrict__ bp, float* __restrict__ out, int Mc)
{
  __shared__ __align__(16) char smem[32768];
  char* Al = smem;
  char* Bl = smem + 16384;

  const int tid = threadIdx.x;
  const int m0 = blockIdx.x * 128;
  const int n0 = blockIdx.y * 128;
  const int wid = tid >> 6, ln = tid & 63;
  const int wm = wid >> 1, wn_ = wid & 1;
  const int lr = ln & 15, lg = ln >> 4;
  const int srow = ln >> 3, sslot = ln & 7;

  f32x4 acc[4][4];
#pragma unroll
  for (int i = 0; i < 4; ++i)
#pragma unroll
    for (int j = 0; j < 4; ++j) acc[i][j] = f32x4{0.f, 0.f, 0.f, 0.f};

  for (int kt = 0; kt < Cc; kt += 64) {
#pragma unroll
    for (int i = 0; i < 4; ++i) {
      int off = (wid * 4 + i) << 10;
      int row = (off >> 7) + srow;
      gload16(att + (size_t)(m0 + row) * Cc + kt + ((sslot ^ (row & 7)) << 3), Al + off);
    }
#pragma unroll
    for (int i = 0; i < 4; ++i) {
      int off = (wid * 4 + i) << 10;
      int row = (off >> 7) + srow;
      gload16(wpb + (size_t)(n0 + row) * Cc + kt + ((sslot ^ (row & 7)) << 3), Bl + off);
    }
    __syncthreads();
#pragma unroll
    for (int ks = 0; ks < 2; ++ks) {
      bf16x8 af[4], bfr[4];
#pragma unroll
      for (int mi = 0; mi < 4; ++mi) {
        int r = wm * 64 + mi * 16 + lr;
        af[mi] = *(const bf16x8*)(Al + r * 128 + (((ks * 4 + lg) ^ (r & 7)) << 4));
      }
#pragma unroll
      for (int ni = 0; ni < 4; ++ni) {
        int r = wn_ * 64 + ni * 16 + lr;
        bfr[ni] = *(const bf16x8*)(Bl + r * 128 + (((ks * 4 + lg) ^ (r & 7)) << 4));
      }
      __builtin_amdgcn_s_setprio(1);
#pragma unroll
      for (int mi = 0; mi < 4; ++mi)
#pragma unroll
        for (int ni = 0; ni < 4; ++ni)
          acc[mi][ni] = MFMA16(af[mi], bfr[ni], acc[mi][ni]);
      __builtin_amdgcn_s_setprio(0);
    }
    __syncthreads();
  }
#pragma unroll
  for (int ni = 0; ni < 4; ++ni) {
    int n = n0 + wn_ * 64 + ni * 16 + lr;
    float bv = bp[n];
#pragma unroll
    for (int mi = 0; mi < 4; ++mi)
#pragma unroll
      for (int j = 0; j < 4; ++j) {
        int m = m0 + wm * 64 + mi * 16 + lg * 4 + j;
        out[(size_t)m * Cc + n] = acc[mi][ni][j] + bv;
      }
  }
}

// ---------------- launch ----------------
extern "C" void kernel_launch(void* const* d_in, const int* in_sizes, int n_in,
                              void* d_out, int out_size, void* d_ws, size_t ws_size,
                              hipStream_t stream) {
  const float* x  = (const float*)d_in[0];
  const float* wq = (const float*)d_in[1];
  const float* wk = (const float*)d_in[2];
  const float* wv = (const float*)d_in[3];
  const float* wp = (const float*)d_in[4];
  const float* bp = (const float*)d_in[5];
  float* out = (float*)d_out;

  char* ws = (char*)d_ws;
  __bf16* wqkvb = (__bf16*)ws;                    // 884736 B
  __bf16* wpb   = (__bf16*)(ws + 884736);         // 294912 B
  char*   dyn   = ws + 1179648;

  // per-chunk bytes = 4 * Mc*384*2 = Bc*786432  (xb aliases att)
  int Bc = 128;
  while (Bc > 1 && 1179648ull + (unsigned long long)Bc * 786432ull > (unsigned long long)ws_size)
    Bc >>= 1;
  const int Mc = Bc * 256;
  __bf16* xb  = (__bf16*)dyn;                             // Mc*384 bf16 (reused as att)
  __bf16* att = xb;
  __bf16* qkv = (__bf16*)(dyn + (size_t)Mc * HD * 2);     // 3 planes of Mc*384 bf16

  prep_w<<<2304, 256, 0, stream>>>(wq, wk, wv, wp, wqkvb, wpb);

  for (int b0 = 0; b0 < 128; b0 += Bc) {
    const float* xc  = x + (size_t)b0 * Tt * Cc;
    float* outc      = out + (size_t)b0 * Tt * Cc;
    xcast<<<Bc * 48, 256, 0, stream>>>(xc, xb);
    gemm_qkv<<<dim3(Mc / 128, 9), 256, 0, stream>>>(xb, wqkvb, qkv, Mc);
    attn_k<<<Bc * Hh, 512, 0, stream>>>(qkv, qkv + (size_t)Mc * HD,
                                        qkv + (size_t)2 * Mc * HD, att);
    gemm_out<<<dim3(Mc / 128, 3), 256, 0, stream>>>(att, wpb, bp, outc, Mc);
  }
}

// Round 8
// 208.189 us; speedup vs baseline: 1.3369x; 1.3369x over previous
//
#include <hip/hip_runtime.h>
#include <hip/hip_bf16.h>

typedef __bf16 bf16x8 __attribute__((ext_vector_type(8)));
typedef __bf16 bf16x4 __attribute__((ext_vector_type(4)));
typedef float  f32x4  __attribute__((ext_vector_type(4)));
typedef int    i32x4  __attribute__((ext_vector_type(4)));

#define MFMA16(a,b,c) __builtin_amdgcn_mfma_f32_16x16x32_bf16((a),(b),(c),0,0,0)

static constexpr int Tt = 256;   // seq len
static constexpr int Cc = 384;   // embed
static constexpr int Hh = 6;     // heads
static constexpr int Dd = 64;    // head dim
static constexpr int HD = 384;   // H*D
static constexpr int NQ = 1152;  // 3*H*D

// async global->LDS, 16B per lane; lds base must be wave-uniform
__device__ __forceinline__ void gload16(const void* g, void* l) {
  __builtin_amdgcn_global_load_lds(
      (const __attribute__((address_space(1))) void*)g,
      (__attribute__((address_space(3))) void*)l, 16, 0, 0);
}

// ---------------- xcast: x fp32 -> bf16 ----------------
__global__ __launch_bounds__(256) void xcast(
    const float* __restrict__ x, __bf16* __restrict__ xb)
{
  size_t i = (size_t)blockIdx.x * 256 + threadIdx.x;
  const float4* p = (const float4*)(x + i * 8);
  float4 a = p[0], b = p[1];
  bf16x8 o;
  o[0] = (__bf16)a.x; o[1] = (__bf16)a.y; o[2] = (__bf16)a.z; o[3] = (__bf16)a.w;
  o[4] = (__bf16)b.x; o[5] = (__bf16)b.y; o[6] = (__bf16)b.z; o[7] = (__bf16)b.w;
  *(bf16x8*)(xb + i * 8) = o;
}

// ---------------- prep: convert/transpose weights to bf16 ----------------
__global__ __launch_bounds__(256) void prep_w(
    const float* __restrict__ wq, const float* __restrict__ wk,
    const float* __restrict__ wv, const float* __restrict__ wp,
    __bf16* __restrict__ wqkvb, __bf16* __restrict__ wpb)
{
  int idx = blockIdx.x * 256 + threadIdx.x;
  const int n1 = NQ * Cc;  // 442368
  if (idx < n1) {
    int n = idx / Cc, c = idx % Cc;
    int which = n / HD, r = n % HD, h = r >> 6, d = r & 63;
    const float* w = which == 0 ? wq : (which == 1 ? wk : wv);
    wqkvb[idx] = (__bf16)w[(h * Cc + c) * Dd + d];
  } else {
    int j = idx - n1;
    if (j < Cc * HD) {
      int co = j / HD, ci = j % HD;
      wpb[j] = (__bf16)wp[ci * Cc + co];
    }
  }
}

// ---------------- GEMM 1: QKV projection ----------------
__global__ __launch_bounds__(256) void gemm_qkv(
    const __bf16* __restrict__ xb, const __bf16* __restrict__ wn,
    __bf16* __restrict__ qkv, int Mc)
{
  __shared__ __align__(16) char smem[36864];
  char* Al = smem;            // [128 rows][128B], slot s holds global slot s^(row&7)
  char* Bl = smem + 16384;

  const int tid = threadIdx.x;
  const int m0 = blockIdx.x * 128;
  const int n0 = blockIdx.y * 128;
  const int wid = tid >> 6, ln = tid & 63;
  const int wm = wid >> 1, wn_ = wid & 1;
  const int lr = ln & 15, lg = ln >> 4;
  const int srow = ln >> 3, sslot = ln & 7;

  f32x4 acc[4][4];
#pragma unroll
  for (int i = 0; i < 4; ++i)
#pragma unroll
    for (int j = 0; j < 4; ++j) acc[i][j] = f32x4{0.f, 0.f, 0.f, 0.f};

  for (int kt = 0; kt < Cc; kt += 64) {
#pragma unroll
    for (int i = 0; i < 4; ++i) {
      int off = (wid * 4 + i) << 10;
      int row = (off >> 7) + srow;
      gload16(xb + (size_t)(m0 + row) * Cc + kt + ((sslot ^ (row & 7)) << 3), Al + off);
    }
#pragma unroll
    for (int i = 0; i < 4; ++i) {
      int off = (wid * 4 + i) << 10;
      int row = (off >> 7) + srow;
      gload16(wn + (size_t)(n0 + row) * Cc + kt + ((sslot ^ (row & 7)) << 3), Bl + off);
    }
    __syncthreads();
#pragma unroll
    for (int ks = 0; ks < 2; ++ks) {
      bf16x8 af[4], bfr[4];
#pragma unroll
      for (int mi = 0; mi < 4; ++mi) {
        int r = wm * 64 + mi * 16 + lr;
        af[mi] = *(const bf16x8*)(Al + r * 128 + (((ks * 4 + lg) ^ (r & 7)) << 4));
      }
#pragma unroll
      for (int ni = 0; ni < 4; ++ni) {
        int r = wn_ * 64 + ni * 16 + lr;
        bfr[ni] = *(const bf16x8*)(Bl + r * 128 + (((ks * 4 + lg) ^ (r & 7)) << 4));
      }
      __builtin_amdgcn_s_setprio(1);
#pragma unroll
      for (int mi = 0; mi < 4; ++mi)
#pragma unroll
        for (int ni = 0; ni < 4; ++ni)
          acc[mi][ni] = MFMA16(af[mi], bfr[ni], acc[mi][ni]);
      __builtin_amdgcn_s_setprio(0);
    }
    __syncthreads();
  }

  // epilogue: stage C tile in LDS, then coalesced 16B scatter-stores
  __bf16* Cl = (__bf16*)smem;  // [128][136] (272B stride), 34816 B
#pragma unroll
  for (int mi = 0; mi < 4; ++mi)
#pragma unroll
    for (int ni = 0; ni < 4; ++ni)
#pragma unroll
      for (int j = 0; j < 4; ++j) {
        int row = wm * 64 + mi * 16 + lg * 4 + j;
        int col = wn_ * 64 + ni * 16 + lr;
        *((__bf16*)((char*)Cl + row * 272 + col * 2)) = (__bf16)acc[mi][ni][j];
      }
  __syncthreads();
#pragma unroll
  for (int p = 0; p < 8; ++p) {
    int row = p * 16 + (tid >> 4);
    int ch = tid & 15;
    bf16x8 v = *(const bf16x8*)((char*)Cl + row * 272 + ch * 16);
    int m = m0 + row, n = n0 + ch * 8;
    int which = n / HD, r = n % HD, h = r >> 6, d = r & 63;
    int bl = m >> 8, t = m & 255;
    *(bf16x8*)(qkv + (size_t)which * ((size_t)Mc * HD) +
               ((size_t)(bl * Hh + h) * Tt + t) * Dd + d) = v;
  }
}

// ---------------- Attention v2d: swapped QK^T, in-register P (no launch_bounds cap) ----------------
__global__ __launch_bounds__(512) void attn_k(
    const __bf16* __restrict__ q, const __bf16* __restrict__ k,
    const __bf16* __restrict__ v, __bf16* __restrict__ att)
{
  __shared__ __align__(128) char smem[65536];
  char* Kl = smem;           // [256 keys][128B], 16B-slot s holds global slot s^(key&7)
  char* Vl = smem + 32768;   // [64][256] bf16 (transposed), byte ^ ((d&7)<<4)  [R2/R3-verified]

  const int bh = blockIdx.x;
  const int tid = threadIdx.x, wid = tid >> 6, lane = tid & 63;
  const int lr = lane & 15, lg = lane >> 4;
  const size_t base = (size_t)bh * (Tt * Dd);

  // stage K: linear dest, pre-swizzled source
#pragma unroll
  for (int i = 0; i < 4; ++i) {
    int off = (wid * 4 + i) << 10;
    int row = (off >> 7) + (lane >> 3);
    int slot = lane & 7;
    gload16(k + base + row * 64 + ((slot ^ (row & 7)) << 3), Kl + off);
  }
  // stage V transposed (scalar writes, swizzled) — verified R2/R3 pattern
#pragma unroll
  for (int i = 0; i < 4; ++i) {
    int chunk = tid + 512 * i;           // 2048 chunks of 8 bf16
    int key = chunk >> 3, d8 = chunk & 7;
    bf16x8 vv = *(const bf16x8*)(v + base + key * 64 + d8 * 8);
#pragma unroll
    for (int e = 0; e < 8; ++e) {
      int d = d8 * 8 + e;
      *(__bf16*)(Vl + ((d * 512 + key * 2) ^ ((d & 7) << 4))) = vv[e];
    }
  }
  __syncthreads();

  const int bl = bh / Hh, h = bh % Hh;

  for (int qi = 0; qi < 2; ++qi) {
    const int qt = (qi == 0) ? wid : 15 - wid;   // q-tile 0..15, balanced pairing
    const int qbase = qt * 16;

    // Q as B-fragment: col = q_local = lr, k = lg*8+e
    bf16x8 qf0 = *(const bf16x8*)(q + base + (qbase + lr) * 64 + lg * 8);
    bf16x8 qf1 = *(const bf16x8*)(q + base + (qbase + lr) * 64 + 32 + lg * 8);

    // swapped QK^T: s[n][j] = S[key = n*16 + 4*lg + j][q = qbase + lr]
    f32x4 s[16];
#pragma unroll
    for (int n = 0; n < 16; ++n) s[n] = f32x4{0.f, 0.f, 0.f, 0.f};
    __builtin_amdgcn_s_setprio(1);
#pragma unroll
    for (int n = 0; n < 16; ++n) {
      if (n <= qt) {
        int rowb = (n * 16 + lr) * 128;
        int swz = (lr & 7) << 4;
        bf16x8 k0 = *(const bf16x8*)(Kl + ((rowb + lg * 16) ^ swz));
        bf16x8 k1 = *(const bf16x8*)(Kl + ((rowb + 64 + lg * 16) ^ swz));
        s[n] = MFMA16(k0, qf0, s[n]);
        s[n] = MFMA16(k1, qf1, s[n]);
      }
    }
    __builtin_amdgcn_s_setprio(0);

    // scale + causal mask (only diagonal tile partially masked)
    float mx = -1e30f;
#pragma unroll
    for (int n = 0; n < 16; ++n) {
      if (n <= qt) {
#pragma unroll
        for (int j = 0; j < 4; ++j) {
          float sv = s[n][j] * 0.125f;
          if (n == qt && 4 * lg + j > lr) sv = -1e30f;
          s[n][j] = sv;
          mx = fmaxf(mx, sv);
        }
      }
    }
    mx = fmaxf(mx, __shfl_xor(mx, 16));
    mx = fmaxf(mx, __shfl_xor(mx, 32));

    // exp + row-sum + pack P to bf16 words (unnormalized; normalize at epilogue)
    float sum = 0.f;
    int w[16][2];
#pragma unroll
    for (int n = 0; n < 16; ++n) {
      if (n <= qt) {
        float e0 = __expf(s[n][0] - mx);
        float e1 = __expf(s[n][1] - mx);
        float e2 = __expf(s[n][2] - mx);
        float e3 = __expf(s[n][3] - mx);
        sum += (e0 + e1) + (e2 + e3);
        union { __bf16 hh[2]; int ii; } u0, u1;
        u0.hh[0] = (__bf16)e0; u0.hh[1] = (__bf16)e1;
        u1.hh[0] = (__bf16)e2; u1.hh[1] = (__bf16)e3;
        w[n][0] = u0.ii;
        w[n][1] = u1.ii;
      } else if (n == (qt | 1)) {
        w[n][0] = 0; w[n][1] = 0;   // zero pad tile read by PV when qt is even
      }
    }
    sum += __shfl_xor(sum, 16);
    sum += __shfl_xor(sum, 32);
    float inv = 1.0f / sum;

    // PV: A = P (shuffle dance, in-register), B = V via swizzled b128 reads
    f32x4 o[4];
#pragma unroll
    for (int dn = 0; dn < 4; ++dn) o[dn] = f32x4{0.f, 0.f, 0.f, 0.f};
    const int kkmax = qt >> 1;
#pragma unroll
    for (int kk = 0; kk < 8; ++kk) {
      if (kk <= kkmax) {
        // A-fragment: lane (lr,lg) needs P[q=lr][key = kk*32 + lg*8 + 2r + {0,1}]
        int s0 = lr + ((lg & 1) << 5);
        int s1 = s0 + 16;
        int hi = lg >> 1;
        int a0 = __shfl(w[2 * kk][0], s0), b0 = __shfl(w[2 * kk + 1][0], s0);
        int a1 = __shfl(w[2 * kk][1], s0), b1 = __shfl(w[2 * kk + 1][1], s0);
        int a2 = __shfl(w[2 * kk][0], s1), b2 = __shfl(w[2 * kk + 1][0], s1);
        int a3 = __shfl(w[2 * kk][1], s1), b3 = __shfl(w[2 * kk + 1][1], s1);
        i32x4 pwv;
        pwv[0] = hi ? b0 : a0;
        pwv[1] = hi ? b1 : a1;
        pwv[2] = hi ? b2 : a2;
        pwv[3] = hi ? b3 : a3;
        bf16x8 pa = __builtin_bit_cast(bf16x8, pwv);

        __builtin_amdgcn_s_setprio(1);
#pragma unroll
        for (int dn = 0; dn < 4; ++dn) {
          int d = dn * 16 + lr;
          bf16x8 vb = *(const bf16x8*)(Vl + ((d * 512 + kk * 64 + lg * 16) ^ ((d & 7) << 4)));
          o[dn] = MFMA16(pa, vb, o[dn]);
        }
        __builtin_amdgcn_s_setprio(0);
      }
    }

    // epilogue: O[q = qbase + 4*lg + j][d = dn*16 + lr], normalized by 1/sum(q)
#pragma unroll
    for (int j = 0; j < 4; ++j) {
      float invj = __shfl(inv, lg * 4 + j, 16);
      int qrow = qbase + lg * 4 + j;
#pragma unroll
      for (int dn = 0; dn < 4; ++dn)
        att[((size_t)(bl * Tt + qrow)) * HD + h * Dd + dn * 16 + lr] =
            (__bf16)(o[dn][j] * invj);
    }
  }
}

// ---------------- GEMM 2: output projection + bias ----------------
__global__ __launch_bounds__(256) void gemm_out(
    const __bf16* __restrict__ att, const __bf16* __restrict__ wpb,
    const float* __restrict__ bp, float* __restrict__ out, int Mc)
{
  __shared__ __align__(16) char smem[32768];
  char* Al = smem;
  char* Bl = smem + 16384;

  const int tid = threadIdx.x;
  const int m0 = blockIdx.x * 128;
  const int n0 = blockIdx.y * 128;
  const int wid = tid >> 6, ln = tid & 63;
  const int wm = wid >> 1, wn_ = wid & 1;
  const int lr = ln & 15, lg = ln >> 4;
  const int srow = ln >> 3, sslot = ln & 7;

  f32x4 acc[4][4];
#pragma unroll
  for (int i = 0; i < 4; ++i)
#pragma unroll
    for (int j = 0; j < 4; ++j) acc[i][j] = f32x4{0.f, 0.f, 0.f, 0.f};

  for (int kt = 0; kt < Cc; kt += 64) {
#pragma unroll
    for (int i = 0; i < 4; ++i) {
      int off = (wid * 4 + i) << 10;
      int row = (off >> 7) + srow;
      gload16(att + (size_t)(m0 + row) * Cc + kt + ((sslot ^ (row & 7)) << 3), Al + off);
    }
#pragma unroll
    for (int i = 0; i < 4; ++i) {
      int off = (wid * 4 + i) << 10;
      int row = (off >> 7) + srow;
      gload16(wpb + (size_t)(n0 + row) * Cc + kt + ((sslot ^ (row & 7)) << 3), Bl + off);
    }
    __syncthreads();
#pragma unroll
    for (int ks = 0; ks < 2; ++ks) {
      bf16x8 af[4], bfr[4];
#pragma unroll
      for (int mi = 0; mi < 4; ++mi) {
        int r = wm * 64 + mi * 16 + lr;
        af[mi] = *(const bf16x8*)(Al + r * 128 + (((ks * 4 + lg) ^ (r & 7)) << 4));
      }
#pragma unroll
      for (int ni = 0; ni < 4; ++ni) {
        int r = wn_ * 64 + ni * 16 + lr;
        bfr[ni] = *(const bf16x8*)(Bl + r * 128 + (((ks * 4 + lg) ^ (r & 7)) << 4));
      }
      __builtin_amdgcn_s_setprio(1);
#pragma unroll
      for (int mi = 0; mi < 4; ++mi)
#pragma unroll
        for (int ni = 0; ni < 4; ++ni)
          acc[mi][ni] = MFMA16(af[mi], bfr[ni], acc[mi][ni]);
      __builtin_amdgcn_s_setprio(0);
    }
    __syncthreads();
  }
#pragma unroll
  for (int ni = 0; ni < 4; ++ni) {
    int n = n0 + wn_ * 64 + ni * 16 + lr;
    float bv = bp[n];
#pragma unroll
    for (int mi = 0; mi < 4; ++mi)
#pragma unroll
      for (int j = 0; j < 4; ++j) {
        int m = m0 + wm * 64 + mi * 16 + lg * 4 + j;
        out[(size_t)m * Cc + n] = acc[mi][ni][j] + bv;
      }
  }
}

// ---------------- launch ----------------
extern "C" void kernel_launch(void* const* d_in, const int* in_sizes, int n_in,
                              void* d_out, int out_size, void* d_ws, size_t ws_size,
                              hipStream_t stream) {
  const float* x  = (const float*)d_in[0];
  const float* wq = (const float*)d_in[1];
  const float* wk = (const float*)d_in[2];
  const float* wv = (const float*)d_in[3];
  const float* wp = (const float*)d_in[4];
  const float* bp = (const float*)d_in[5];
  float* out = (float*)d_out;

  char* ws = (char*)d_ws;
  __bf16* wqkvb = (__bf16*)ws;                    // 884736 B
  __bf16* wpb   = (__bf16*)(ws + 884736);         // 294912 B
  char*   dyn   = ws + 1179648;

  // per-chunk bytes = 4 * Mc*384*2 = Bc*786432  (xb aliases att)
  int Bc = 128;
  while (Bc > 1 && 1179648ull + (unsigned long long)Bc * 786432ull > (unsigned long long)ws_size)
    Bc >>= 1;
  const int Mc = Bc * 256;
  __bf16* xb  = (__bf16*)dyn;                             // Mc*384 bf16 (reused as att)
  __bf16* att = xb;
  __bf16* qkv = (__bf16*)(dyn + (size_t)Mc * HD * 2);     // 3 planes of Mc*384 bf16

  prep_w<<<2304, 256, 0, stream>>>(wq, wk, wv, wp, wqkvb, wpb);

  for (int b0 = 0; b0 < 128; b0 += Bc) {
    const float* xc  = x + (size_t)b0 * Tt * Cc;
    float* outc      = out + (size_t)b0 * Tt * Cc;
    xcast<<<Bc * 48, 256, 0, stream>>>(xc, xb);
    gemm_qkv<<<dim3(Mc / 128, 9), 256, 0, stream>>>(xb, wqkvb, qkv, Mc);
    attn_k<<<Bc * Hh, 512, 0, stream>>>(qkv, qkv + (size_t)Mc * HD,
                                        qkv + (size_t)2 * Mc * HD, att);
    gemm_out<<<dim3(Mc / 128, 3), 256, 0, stream>>>(att, wpb, bp, outc, Mc);
  }
}

// Round 9
// 203.338 us; speedup vs baseline: 1.3688x; 1.0239x over previous
//
#include <hip/hip_runtime.h>
#include <hip/hip_bf16.h>

typedef __bf16 bf16x8 __attribute__((ext_vector_type(8)));
typedef __bf16 bf16x4 __attribute__((ext_vector_type(4)));
typedef float  f32x4  __attribute__((ext_vector_type(4)));
typedef int    i32x4  __attribute__((ext_vector_type(4)));

#define MFMA16(a,b,c) __builtin_amdgcn_mfma_f32_16x16x32_bf16((a),(b),(c),0,0,0)

static constexpr int Tt = 256;   // seq len
static constexpr int Cc = 384;   // embed
static constexpr int Hh = 6;     // heads
static constexpr int Dd = 64;    // head dim
static constexpr int HD = 384;   // H*D
static constexpr int NQ = 1152;  // 3*H*D

// async global->LDS, 16B per lane; lds base must be wave-uniform
__device__ __forceinline__ void gload16(const void* g, void* l) {
  __builtin_amdgcn_global_load_lds(
      (const __attribute__((address_space(1))) void*)g,
      (__attribute__((address_space(3))) void*)l, 16, 0, 0);
}

// stage a 128x64 bf16 tile pair (A,B) into LDS at lbase / lbase+16384,
// linear dest + pre-swizzled source (rule #21). a,b already offset to (row0, kt).
__device__ __forceinline__ void stage_ab(const __bf16* a, const __bf16* b,
                                         char* lbase, int wid, int srow, int sslot) {
#pragma unroll
  for (int i = 0; i < 4; ++i) {
    int loff = (wid * 4 + i) << 10;
    int row = (loff >> 7) + srow;
    int co = (sslot ^ (row & 7)) << 3;
    gload16(a + (size_t)row * Cc + co, lbase + loff);
    gload16(b + (size_t)row * Cc + co, lbase + 16384 + loff);
  }
}

// ---------------- xcast: x fp32 -> bf16 ----------------
__global__ __launch_bounds__(256) void xcast(
    const float* __restrict__ x, __bf16* __restrict__ xb)
{
  size_t i = (size_t)blockIdx.x * 256 + threadIdx.x;
  const float4* p = (const float4*)(x + i * 8);
  float4 a = p[0], b = p[1];
  bf16x8 o;
  o[0] = (__bf16)a.x; o[1] = (__bf16)a.y; o[2] = (__bf16)a.z; o[3] = (__bf16)a.w;
  o[4] = (__bf16)b.x; o[5] = (__bf16)b.y; o[6] = (__bf16)b.z; o[7] = (__bf16)b.w;
  *(bf16x8*)(xb + i * 8) = o;
}

// ---------------- prep_w2: coalesced 64x64 tile transpose to bf16 ----------------
// blocks 0..107: wq/wk/wv [h][c][d] -> wqkvb[n=which*384+h*64+d][c]
// blocks 108..143: wp [ci][co] -> wpb[co][ci]
__global__ __launch_bounds__(256) void prep_w2(
    const float* __restrict__ wq, const float* __restrict__ wk,
    const float* __restrict__ wv, const float* __restrict__ wp,
    __bf16* __restrict__ wqkvb, __bf16* __restrict__ wpb)
{
  __shared__ __bf16 t[64][72];   // 72: 144B rows, 16B-aligned for b128 reads
  const int b = blockIdx.x, tid = threadIdx.x;
  const float* src; __bf16* dst;
  int row0, col0, rs, dr0, dc0;
  if (b < 108) {
    int which = b / 36, rem = b % 36, h = rem / 6, ct = rem % 6;
    src = which == 0 ? wq : (which == 1 ? wk : wv);
    row0 = h * 384 + ct * 64; col0 = 0; rs = 64;
    dst = wqkvb; dr0 = which * 384 + h * 64; dc0 = ct * 64;
  } else {
    int b2 = b - 108, rt = b2 / 6, ct2 = b2 % 6;
    src = wp; row0 = ct2 * 64; col0 = rt * 64; rs = 384;
    dst = wpb; dr0 = rt * 64; dc0 = ct2 * 64;
  }
  const int tr = tid >> 6, tc = tid & 63;
#pragma unroll
  for (int i = 0; i < 16; ++i) {
    int r = i * 4 + tr;
    t[tc][r] = (__bf16)src[(size_t)(row0 + r) * rs + col0 + tc];
  }
  __syncthreads();
#pragma unroll
  for (int i = 0; i < 2; ++i) {
    int chunk = tid + 256 * i;        // 512 chunks of 8 bf16
    int r = chunk >> 3, c8 = chunk & 7;
    bf16x8 v = *(const bf16x8*)&t[r][c8 * 8];
    *(bf16x8*)(dst + (size_t)(dr0 + r) * 384 + dc0 + c8 * 8) = v;
  }
}

// ---------------- GEMM 1: QKV projection (2-phase dbuf) ----------------
__global__ __launch_bounds__(256) void gemm_qkv(
    const __bf16* __restrict__ xb, const __bf16* __restrict__ wn,
    __bf16* __restrict__ qkv, int Mc)
{
  __shared__ __align__(16) char smem[65536];  // 2 x (A 16K + B 16K)

  const int tid = threadIdx.x;
  const int m0 = blockIdx.x * 128;
  const int n0 = blockIdx.y * 128;
  const int wid = tid >> 6, ln = tid & 63;
  const int wm = wid >> 1, wn_ = wid & 1;
  const int lr = ln & 15, lg = ln >> 4;
  const int srow = ln >> 3, sslot = ln & 7;

  const __bf16* a0 = xb + (size_t)m0 * Cc;
  const __bf16* b0 = wn + (size_t)n0 * Cc;

  f32x4 acc[4][4];
#pragma unroll
  for (int i = 0; i < 4; ++i)
#pragma unroll
    for (int j = 0; j < 4; ++j) acc[i][j] = f32x4{0.f, 0.f, 0.f, 0.f};

  stage_ab(a0, b0, smem, wid, srow, sslot);
  __syncthreads();
#pragma unroll
  for (int t = 0; t < 6; ++t) {
    const int base = (t & 1) * 32768;
    if (t < 5)
      stage_ab(a0 + (t + 1) * 64, b0 + (t + 1) * 64,
               smem + (((t + 1) & 1) * 32768), wid, srow, sslot);
    char* Al = smem + base;
    char* Bl = smem + base + 16384;
#pragma unroll
    for (int ks = 0; ks < 2; ++ks) {
      bf16x8 af[4], bfr[4];
#pragma unroll
      for (int mi = 0; mi < 4; ++mi) {
        int r = wm * 64 + mi * 16 + lr;
        af[mi] = *(const bf16x8*)(Al + r * 128 + (((ks * 4 + lg) ^ (r & 7)) << 4));
      }
#pragma unroll
      for (int ni = 0; ni < 4; ++ni) {
        int r = wn_ * 64 + ni * 16 + lr;
        bfr[ni] = *(const bf16x8*)(Bl + r * 128 + (((ks * 4 + lg) ^ (r & 7)) << 4));
      }
      __builtin_amdgcn_s_setprio(1);
#pragma unroll
      for (int mi = 0; mi < 4; ++mi)
#pragma unroll
        for (int ni = 0; ni < 4; ++ni)
          acc[mi][ni] = MFMA16(af[mi], bfr[ni], acc[mi][ni]);
      __builtin_amdgcn_s_setprio(0);
    }
    __syncthreads();   // drains this iter's stage + read-safety for rebuffer
  }

  // epilogue: stage C tile in LDS, then coalesced 16B scatter-stores
  __bf16* Cl = (__bf16*)smem;  // [128][136] (272B stride), 34816 B
#pragma unroll
  for (int mi = 0; mi < 4; ++mi)
#pragma unroll
    for (int ni = 0; ni < 4; ++ni)
#pragma unroll
      for (int j = 0; j < 4; ++j) {
        int row = wm * 64 + mi * 16 + lg * 4 + j;
        int col = wn_ * 64 + ni * 16 + lr;
        *((__bf16*)((char*)Cl + row * 272 + col * 2)) = (__bf16)acc[mi][ni][j];
      }
  __syncthreads();
#pragma unroll
  for (int p = 0; p < 8; ++p) {
    int row = p * 16 + (tid >> 4);
    int ch = tid & 15;
    bf16x8 v = *(const bf16x8*)((char*)Cl + row * 272 + ch * 16);
    int m = m0 + row, n = n0 + ch * 8;
    int which = n / HD, r = n % HD, h = r >> 6, d = r & 63;
    int bl = m >> 8, t = m & 255;
    *(bf16x8*)(qkv + (size_t)which * ((size_t)Mc * HD) +
               ((size_t)(bl * Hh + h) * Tt + t) * Dd + d) = v;
  }
}

// ---------------- Attention v2d: swapped QK^T, in-register P ----------------
__global__ __launch_bounds__(512) void attn_k(
    const __bf16* __restrict__ q, const __bf16* __restrict__ k,
    const __bf16* __restrict__ v, __bf16* __restrict__ att)
{
  __shared__ __align__(128) char smem[65536];
  char* Kl = smem;           // [256 keys][128B], 16B-slot s holds global slot s^(key&7)
  char* Vl = smem + 32768;   // [64][256] bf16 (transposed), byte ^ ((d&7)<<4)

  const int bh = blockIdx.x;
  const int tid = threadIdx.x, wid = tid >> 6, lane = tid & 63;
  const int lr = lane & 15, lg = lane >> 4;
  const size_t base = (size_t)bh * (Tt * Dd);

  // stage K: linear dest, pre-swizzled source
#pragma unroll
  for (int i = 0; i < 4; ++i) {
    int off = (wid * 4 + i) << 10;
    int row = (off >> 7) + (lane >> 3);
    int slot = lane & 7;
    gload16(k + base + row * 64 + ((slot ^ (row & 7)) << 3), Kl + off);
  }
  // stage V transposed (scalar writes, swizzled)
#pragma unroll
  for (int i = 0; i < 4; ++i) {
    int chunk = tid + 512 * i;           // 2048 chunks of 8 bf16
    int key = chunk >> 3, d8 = chunk & 7;
    bf16x8 vv = *(const bf16x8*)(v + base + key * 64 + d8 * 8);
#pragma unroll
    for (int e = 0; e < 8; ++e) {
      int d = d8 * 8 + e;
      *(__bf16*)(Vl + ((d * 512 + key * 2) ^ ((d & 7) << 4))) = vv[e];
    }
  }
  __syncthreads();

  const int bl = bh / Hh, h = bh % Hh;

  for (int qi = 0; qi < 2; ++qi) {
    const int qt = (qi == 0) ? wid : 15 - wid;   // q-tile 0..15, balanced pairing
    const int qbase = qt * 16;

    // Q as B-fragment: col = q_local = lr, k = lg*8+e
    bf16x8 qf0 = *(const bf16x8*)(q + base + (qbase + lr) * 64 + lg * 8);
    bf16x8 qf1 = *(const bf16x8*)(q + base + (qbase + lr) * 64 + 32 + lg * 8);

    // swapped QK^T: s[n][j] = S[key = n*16 + 4*lg + j][q = qbase + lr]
    f32x4 s[16];
#pragma unroll
    for (int n = 0; n < 16; ++n) s[n] = f32x4{0.f, 0.f, 0.f, 0.f};
    __builtin_amdgcn_s_setprio(1);
#pragma unroll
    for (int n = 0; n < 16; ++n) {
      if (n <= qt) {
        int rowb = (n * 16 + lr) * 128;
        int swz = (lr & 7) << 4;
        bf16x8 k0 = *(const bf16x8*)(Kl + ((rowb + lg * 16) ^ swz));
        bf16x8 k1 = *(const bf16x8*)(Kl + ((rowb + 64 + lg * 16) ^ swz));
        s[n] = MFMA16(k0, qf0, s[n]);
        s[n] = MFMA16(k1, qf1, s[n]);
      }
    }
    __builtin_amdgcn_s_setprio(0);

    // scale + causal mask (only diagonal tile partially masked)
    float mx = -1e30f;
#pragma unroll
    for (int n = 0; n < 16; ++n) {
      if (n <= qt) {
#pragma unroll
        for (int j = 0; j < 4; ++j) {
          float sv = s[n][j] * 0.125f;
          if (n == qt && 4 * lg + j > lr) sv = -1e30f;
          s[n][j] = sv;
          mx = fmaxf(mx, sv);
        }
      }
    }
    mx = fmaxf(mx, __shfl_xor(mx, 16));
    mx = fmaxf(mx, __shfl_xor(mx, 32));

    // exp + row-sum + pack P to bf16 words (unnormalized; normalize at epilogue)
    float sum = 0.f;
    int w[16][2];
#pragma unroll
    for (int n = 0; n < 16; ++n) {
      if (n <= qt) {
        float e0 = __expf(s[n][0] - mx);
        float e1 = __expf(s[n][1] - mx);
        float e2 = __expf(s[n][2] - mx);
        float e3 = __expf(s[n][3] - mx);
        sum += (e0 + e1) + (e2 + e3);
        union { __bf16 hh[2]; int ii; } u0, u1;
        u0.hh[0] = (__bf16)e0; u0.hh[1] = (__bf16)e1;
        u1.hh[0] = (__bf16)e2; u1.hh[1] = (__bf16)e3;
        w[n][0] = u0.ii;
        w[n][1] = u1.ii;
      } else if (n == (qt | 1)) {
        w[n][0] = 0; w[n][1] = 0;   // zero pad tile read by PV when qt is even
      }
    }
    sum += __shfl_xor(sum, 16);
    sum += __shfl_xor(sum, 32);
    float inv = 1.0f / sum;

    // PV: A = P (shuffle dance, in-register), B = V via swizzled b128 reads
    f32x4 o[4];
#pragma unroll
    for (int dn = 0; dn < 4; ++dn) o[dn] = f32x4{0.f, 0.f, 0.f, 0.f};
    const int kkmax = qt >> 1;
#pragma unroll
    for (int kk = 0; kk < 8; ++kk) {
      if (kk <= kkmax) {
        // A-fragment: lane (lr,lg) needs P[q=lr][key = kk*32 + lg*8 + 2r + {0,1}]
        int s0 = lr + ((lg & 1) << 5);
        int s1 = s0 + 16;
        int hi = lg >> 1;
        int a0 = __shfl(w[2 * kk][0], s0), b0 = __shfl(w[2 * kk + 1][0], s0);
        int a1 = __shfl(w[2 * kk][1], s0), b1 = __shfl(w[2 * kk + 1][1], s0);
        int a2 = __shfl(w[2 * kk][0], s1), b2 = __shfl(w[2 * kk + 1][0], s1);
        int a3 = __shfl(w[2 * kk][1], s1), b3 = __shfl(w[2 * kk + 1][1], s1);
        i32x4 pwv;
        pwv[0] = hi ? b0 : a0;
        pwv[1] = hi ? b1 : a1;
        pwv[2] = hi ? b2 : a2;
        pwv[3] = hi ? b3 : a3;
        bf16x8 pa = __builtin_bit_cast(bf16x8, pwv);

        __builtin_amdgcn_s_setprio(1);
#pragma unroll
        for (int dn = 0; dn < 4; ++dn) {
          int d = dn * 16 + lr;
          bf16x8 vb = *(const bf16x8*)(Vl + ((d * 512 + kk * 64 + lg * 16) ^ ((d & 7) << 4)));
          o[dn] = MFMA16(pa, vb, o[dn]);
        }
        __builtin_amdgcn_s_setprio(0);
      }
    }

    // epilogue: O[q = qbase + 4*lg + j][d = dn*16 + lr], normalized by 1/sum(q)
#pragma unroll
    for (int j = 0; j < 4; ++j) {
      float invj = __shfl(inv, lg * 4 + j, 16);
      int qrow = qbase + lg * 4 + j;
#pragma unroll
      for (int dn = 0; dn < 4; ++dn)
        att[((size_t)(bl * Tt + qrow)) * HD + h * Dd + dn * 16 + lr] =
            (__bf16)(o[dn][j] * invj);
    }
  }
}

// ---------------- GEMM 2: output projection + bias (2-phase dbuf) ----------------
__global__ __launch_bounds__(256) void gemm_out(
    const __bf16* __restrict__ att, const __bf16* __restrict__ wpb,
    const float* __restrict__ bp, float* __restrict__ out, int Mc)
{
  __shared__ __align__(16) char smem[65536];

  const int tid = threadIdx.x;
  const int m0 = blockIdx.x * 128;
  const int n0 = blockIdx.y * 128;
  const int wid = tid >> 6, ln = tid & 63;
  const int wm = wid >> 1, wn_ = wid & 1;
  const int lr = ln & 15, lg = ln >> 4;
  const int srow = ln >> 3, sslot = ln & 7;

  const __bf16* a0 = att + (size_t)m0 * Cc;
  const __bf16* b0 = wpb + (size_t)n0 * Cc;

  f32x4 acc[4][4];
#pragma unroll
  for (int i = 0; i < 4; ++i)
#pragma unroll
    for (int j = 0; j < 4; ++j) acc[i][j] = f32x4{0.f, 0.f, 0.f, 0.f};

  stage_ab(a0, b0, smem, wid, srow, sslot);
  __syncthreads();
#pragma unroll
  for (int t = 0; t < 6; ++t) {
    const int base = (t & 1) * 32768;
    if (t < 5)
      stage_ab(a0 + (t + 1) * 64, b0 + (t + 1) * 64,
               smem + (((t + 1) & 1) * 32768), wid, srow, sslot);
    char* Al = smem + base;
    char* Bl = smem + base + 16384;
#pragma unroll
    for (int ks = 0; ks < 2; ++ks) {
      bf16x8 af[4], bfr[4];
#pragma unroll
      for (int mi = 0; mi < 4; ++mi) {
        int r = wm * 64 + mi * 16 + lr;
        af[mi] = *(const bf16x8*)(Al + r * 128 + (((ks * 4 + lg) ^ (r & 7)) << 4));
      }
#pragma unroll
      for (int ni = 0; ni < 4; ++ni) {
        int r = wn_ * 64 + ni * 16 + lr;
        bfr[ni] = *(const bf16x8*)(Bl + r * 128 + (((ks * 4 + lg) ^ (r & 7)) << 4));
      }
      __builtin_amdgcn_s_setprio(1);
#pragma unroll
      for (int mi = 0; mi < 4; ++mi)
#pragma unroll
        for (int ni = 0; ni < 4; ++ni)
          acc[mi][ni] = MFMA16(af[mi], bfr[ni], acc[mi][ni]);
      __builtin_amdgcn_s_setprio(0);
    }
    __syncthreads();
  }
#pragma unroll
  for (int ni = 0; ni < 4; ++ni) {
    int n = n0 + wn_ * 64 + ni * 16 + lr;
    float bv = bp[n];
#pragma unroll
    for (int mi = 0; mi < 4; ++mi)
#pragma unroll
      for (int j = 0; j < 4; ++j) {
        int m = m0 + wm * 64 + mi * 16 + lg * 4 + j;
        out[(size_t)m * Cc + n] = acc[mi][ni][j] + bv;
      }
  }
}

// ---------------- launch ----------------
extern "C" void kernel_launch(void* const* d_in, const int* in_sizes, int n_in,
                              void* d_out, int out_size, void* d_ws, size_t ws_size,
                              hipStream_t stream) {
  const float* x  = (const float*)d_in[0];
  const float* wq = (const float*)d_in[1];
  const float* wk = (const float*)d_in[2];
  const float* wv = (const float*)d_in[3];
  const float* wp = (const float*)d_in[4];
  const float* bp = (const float*)d_in[5];
  float* out = (float*)d_out;

  char* ws = (char*)d_ws;
  __bf16* wqkvb = (__bf16*)ws;                    // 884736 B
  __bf16* wpb   = (__bf16*)(ws + 884736);         // 294912 B
  char*   dyn   = ws + 1179648;

  // per-chunk bytes = 4 * Mc*384*2 = Bc*786432  (xb aliases att)
  int Bc = 128;
  while (Bc > 1 && 1179648ull + (unsigned long long)Bc * 786432ull > (unsigned long long)ws_size)
    Bc >>= 1;
  const int Mc = Bc * 256;
  __bf16* xb  = (__bf16*)dyn;                             // Mc*384 bf16 (reused as att)
  __bf16* att = xb;
  __bf16* qkv = (__bf16*)(dyn + (size_t)Mc * HD * 2);     // 3 planes of Mc*384 bf16

  prep_w2<<<144, 256, 0, stream>>>(wq, wk, wv, wp, wqkvb, wpb);

  for (int b0 = 0; b0 < 128; b0 += Bc) {
    const float* xc  = x + (size_t)b0 * Tt * Cc;
    float* outc      = out + (size_t)b0 * Tt * Cc;
    xcast<<<Bc * 48, 256, 0, stream>>>(xc, xb);
    gemm_qkv<<<dim3(Mc / 128, 9), 256, 0, stream>>>(xb, wqkvb, qkv, Mc);
    attn_k<<<Bc * Hh, 512, 0, stream>>>(qkv, qkv + (size_t)Mc * HD,
                                        qkv + (size_t)2 * Mc * HD, att);
    gemm_out<<<dim3(Mc / 128, 3), 256, 0, stream>>>(att, wpb, bp, outc, Mc);
  }
}